// Round 11
// baseline (655.759 us; speedup 1.0000x reference)
//
#include <hip/hip_runtime.h>
#include <math.h>

#define D 64
#define R 5
#define BLOCK 256
#define NBLOCKS 512
#define WPB (BLOCK / 64)

typedef __attribute__((ext_vector_type(8))) short short8;
typedef __attribute__((ext_vector_type(4))) float f32x4;

__device__ __forceinline__ unsigned short f2bf(float x) {
    unsigned u = __builtin_bit_cast(unsigned, x);
    u = (u + 0x7FFFu + ((u >> 16) & 1u)) >> 16;   // RNE
    return (unsigned short)u;
}
__device__ __forceinline__ float bf2f(unsigned short h) {
    unsigned u = ((unsigned)h) << 16;
    return __builtin_bit_cast(float, u);
}
__device__ __forceinline__ float dot4(f32x4 a, float4 u) {
    float p = a[0] * u.x;
    p = fmaf(a[1], u.y, p);
    p = fmaf(a[2], u.z, p);
    p = fmaf(a[3], u.w, p);
    return p;
}

// HARD CONSTRAINT (R3/R6/R8/R9): allocator pegs at 128 VGPR and spills rather
// than exceed it, regardless of launch_bounds/waves_per_eu hints. Keep the
// peak live set <= ~110 regs. Pipeline payload: next tile's vs+us (32 regs)
// in flight during the MFMA block; raw vs of current tile dies at the split.
__global__ __launch_bounds__(BLOCK, 2)
void bidecoder_mfma(const float* __restrict__ ufeat,
                    const float* __restrict__ ifeat,
                    const float* __restrict__ Ps,
                    const int* __restrict__ src,
                    const int* __restrict__ dst,
                    float* __restrict__ out,
                    int E, int NT, int TPB)
{
    __shared__ short plds[40960];   // 80 KB: bf16 hi/lo P fragments

    const int tid = threadIdx.x;

    // one-time P staging: fp32 -> bf16 hi/lo in fragment-ready layout
    // (validated R8: absmax identical to fp32 baseline -> k-order cancellation holds)
    for (int i = tid; i < R * D * D; i += BLOCK) {
        const int r = i >> 12, d = (i >> 6) & 63, f = i & 63;
        const float val = Ps[i];
        const unsigned short hi = f2bf(val);
        const unsigned short lo = f2bf(val - bf2f(hi));
        const int s = f >> 5, g = (f >> 3) & 3, j = f & 7;
        const int Mt = d >> 4;
        const int lane = (d & 15) | (g << 4);
        const int slot = lane * 8 + j;
        const int fbH = (r * 2 + s) * 4 + Mt;
        plds[fbH * 512 + slot]           = (short)hi;
        plds[(fbH + R * 8) * 512 + slot] = (short)lo;
    }
    __syncthreads();   // last barrier in kernel; divergent exits below are safe

    const int l  = tid & 63;
    const int wv = tid >> 6;
    const int li = l & 15;
    const int lg = l >> 4;

    const int t0 = blockIdx.x * TPB;
    int t1 = t0 + TPB; if (t1 > NT) t1 = NT;

    int t = t0 + wv;
    if (t >= t1) return;

    // ---- preload tile t: vs (4xfloat4) + us (4xfloat4) ----
    int ecur = t * 16 + li;
    const int es0 = (ecur < E) ? ecur : (E - 1);
    const float* vrow0 = ifeat + (size_t)dst[es0] * D;
    const float* urow0 = ufeat + (size_t)src[es0] * D;
    float4 va0 = *reinterpret_cast<const float4*>(vrow0 + lg * 8);
    float4 va1 = *reinterpret_cast<const float4*>(vrow0 + lg * 8 + 4);
    float4 va2 = *reinterpret_cast<const float4*>(vrow0 + 32 + lg * 8);
    float4 va3 = *reinterpret_cast<const float4*>(vrow0 + 32 + lg * 8 + 4);
    float4 ua0 = *reinterpret_cast<const float4*>(urow0 + 0 * 16 + lg * 4);
    float4 ua1 = *reinterpret_cast<const float4*>(urow0 + 1 * 16 + lg * 4);
    float4 ua2 = *reinterpret_cast<const float4*>(urow0 + 2 * 16 + lg * 4);
    float4 ua3 = *reinterpret_cast<const float4*>(urow0 + 3 * 16 + lg * 4);

    while (true) {
        // ---- split current vs -> bf16 hi/lo B-fragments (raw vs dies here) ----
        short8 vhi[2], vlo[2];
        {
            const float c0[8] = {va0.x, va0.y, va0.z, va0.w, va1.x, va1.y, va1.z, va1.w};
            const float c1[8] = {va2.x, va2.y, va2.z, va2.w, va3.x, va3.y, va3.z, va3.w};
            #pragma unroll
            for (int j = 0; j < 8; ++j) {
                const unsigned short h0 = f2bf(c0[j]);
                vhi[0][j] = (short)h0;
                vlo[0][j] = (short)f2bf(c0[j] - bf2f(h0));
                const unsigned short h1 = f2bf(c1[j]);
                vhi[1][j] = (short)h1;
                vlo[1][j] = (short)f2bf(c1[j] - bf2f(h1));
            }
        }

        // ---- prefetch tile t+WPB (idx -> rows); in flight during MFMAs ----
        const int tn = t + WPB;
        const bool more = (tn < t1);
        const int tp = more ? tn : t;                 // clamp: harmless reload
        const int enext = tp * 16 + li;
        const int es2 = (enext < E) ? enext : (E - 1);
        const float* vrowB = ifeat + (size_t)dst[es2] * D;
        const float* urowB = ufeat + (size_t)src[es2] * D;
        float4 vb0 = *reinterpret_cast<const float4*>(vrowB + lg * 8);
        float4 vb1 = *reinterpret_cast<const float4*>(vrowB + lg * 8 + 4);
        float4 vb2 = *reinterpret_cast<const float4*>(vrowB + 32 + lg * 8);
        float4 vb3 = *reinterpret_cast<const float4*>(vrowB + 32 + lg * 8 + 4);
        float4 ub0 = *reinterpret_cast<const float4*>(urowB + 0 * 16 + lg * 4);
        float4 ub1 = *reinterpret_cast<const float4*>(urowB + 1 * 16 + lg * 4);
        float4 ub2 = *reinterpret_cast<const float4*>(urowB + 2 * 16 + lg * 4);
        float4 ub3 = *reinterpret_cast<const float4*>(urowB + 3 * 16 + lg * 4);

        // ---- MFMA block + per-r Hadamard (uses ua*, ready since last iter) ----
        float scores[R];
        #pragma unroll
        for (int r = 0; r < R; ++r) {
            f32x4 acc[4] = { {0,0,0,0},{0,0,0,0},{0,0,0,0},{0,0,0,0} };
            #pragma unroll
            for (int s = 0; s < 2; ++s) {
                #pragma unroll
                for (int Mt = 0; Mt < 4; ++Mt) {
                    const int fbH = (r * 2 + s) * 4 + Mt;
                    const short8 aHi = *reinterpret_cast<const short8*>(&plds[fbH * 512 + l * 8]);
                    const short8 aLo = *reinterpret_cast<const short8*>(&plds[(fbH + R * 8) * 512 + l * 8]);
                    acc[Mt] = __builtin_amdgcn_mfma_f32_16x16x32_bf16(aHi, vhi[s], acc[Mt], 0, 0, 0);
                    acc[Mt] = __builtin_amdgcn_mfma_f32_16x16x32_bf16(aLo, vhi[s], acc[Mt], 0, 0, 0);
                    acc[Mt] = __builtin_amdgcn_mfma_f32_16x16x32_bf16(aHi, vlo[s], acc[Mt], 0, 0, 0);
                }
            }
            float part = dot4(acc[0], ua0);
            part += dot4(acc[1], ua1);
            part += dot4(acc[2], ua2);
            part += dot4(acc[3], ua3);
            part += __shfl_xor(part, 16);
            part += __shfl_xor(part, 32);
            scores[r] = part;
        }

        // ---- softmax over R + expected rating ----
        float m = scores[0];
        #pragma unroll
        for (int r = 1; r < R; ++r) m = fmaxf(m, scores[r]);
        float ssum = 0.f, num = 0.f;
        #pragma unroll
        for (int r = 0; r < R; ++r) {
            const float p = expf(scores[r] - m);
            ssum += p;
            num = fmaf((float)(r + 1), p, num);
        }
        if (lg == 0 && ecur < E) out[ecur] = num / ssum;

        if (!more) break;
        t = tn; ecur = enext;
        va0 = vb0; va1 = vb1; va2 = vb2; va3 = vb3;
        ua0 = ub0; ua1 = ub1; ua2 = ub2; ua3 = ub3;
    }
}

extern "C" void kernel_launch(void* const* d_in, const int* in_sizes, int n_in,
                              void* d_out, int out_size, void* d_ws, size_t ws_size,
                              hipStream_t stream)
{
    const float* ufeat = (const float*)d_in[0];
    const float* ifeat = (const float*)d_in[1];
    const float* Ps    = (const float*)d_in[2];
    const int*   src   = (const int*)d_in[3];
    const int*   dst   = (const int*)d_in[4];
    float*       out   = (float*)d_out;
    const int E   = in_sizes[3];
    const int NT  = (E + 15) / 16;
    const int TPB = (NT + NBLOCKS - 1) / NBLOCKS;
    hipLaunchKernelGGL(bidecoder_mfma, dim3(NBLOCKS), dim3(BLOCK), 0, stream,
                       ufeat, ifeat, Ps, src, dst, out, E, NT, TPB);
}

// Round 12
// 221.658 us; speedup vs baseline: 2.9584x; 2.9584x over previous
//
#include <hip/hip_runtime.h>
#include <math.h>

#define D 64
#define R 5
#define BLOCK 256
#define NBLOCKS 512
#define WPB (BLOCK / 64)

typedef __attribute__((ext_vector_type(8))) short short8;
typedef __attribute__((ext_vector_type(4))) float f32x4;

__device__ __forceinline__ unsigned short f2bf(float x) {
    unsigned u = __builtin_bit_cast(unsigned, x);
    u = (u + 0x7FFFu + ((u >> 16) & 1u)) >> 16;   // RNE
    return (unsigned short)u;
}
__device__ __forceinline__ float bf2f(unsigned short h) {
    unsigned u = ((unsigned)h) << 16;
    return __builtin_bit_cast(float, u);
}
__device__ __forceinline__ float dot4(f32x4 a, float4 u) {
    float p = a[0] * u.x;
    p = fmaf(a[1], u.y, p);
    p = fmaf(a[2], u.z, p);
    p = fmaf(a[3], u.w, p);
    return p;
}

// split one float into bf16 hi/lo lane of a short8
#define SPLIT8(dsthi, dstlo, j, val) { \
    const unsigned short h__ = f2bf(val); \
    dsthi[j] = (short)h__; \
    dstlo[j] = (short)f2bf((val) - bf2f(h__)); }

// one Mt sub-block: 2 LDS b128 reads + 3 MFMAs (hi*hi + lo*hi + hi*lo)
#define MBLK(accv, fb, vhiS, vloS) { \
    const short8 aH = *reinterpret_cast<const short8*>(&plds[(fb) * 512 + l * 8]); \
    const short8 aL = *reinterpret_cast<const short8*>(&plds[((fb) + 40) * 512 + l * 8]); \
    accv = __builtin_amdgcn_mfma_f32_16x16x32_bf16(aH, vhiS, accv, 0, 0, 0); \
    accv = __builtin_amdgcn_mfma_f32_16x16x32_bf16(aL, vhiS, accv, 0, 0, 0); \
    accv = __builtin_amdgcn_mfma_f32_16x16x32_bf16(aH, vloS, accv, 0, 0, 0); }

// HARD CONSTRAINT (R3/R6/R8/R9/R11): allocator pegs at 128 VGPR and spills
// rather than exceed. Fully-unrolled 5-r MFMA loop lets the scheduler hoist
// 80 ds_reads -> 64+ transient regs -> spill. Fix: runtime r-loop (unroll 1)
// + online softmax (no scores[] array) + sched_barrier between s-halves.
__global__ __launch_bounds__(BLOCK, 2)
void bidecoder_mfma(const float* __restrict__ ufeat,
                    const float* __restrict__ ifeat,
                    const float* __restrict__ Ps,
                    const int* __restrict__ src,
                    const int* __restrict__ dst,
                    float* __restrict__ out,
                    int E, int NT, int TPB)
{
    __shared__ short plds[40960];   // 80 KB: bf16 hi/lo P fragments

    const int tid = threadIdx.x;

    // one-time P staging: fp32 -> bf16 hi/lo in fragment-ready layout
    // (validated R8: absmax identical to fp32 baseline)
    for (int i = tid; i < R * D * D; i += BLOCK) {
        const int r = i >> 12, d = (i >> 6) & 63, f = i & 63;
        const float val = Ps[i];
        const unsigned short hi = f2bf(val);
        const unsigned short lo = f2bf(val - bf2f(hi));
        const int s = f >> 5, g = (f >> 3) & 3, j = f & 7;
        const int Mt = d >> 4;
        const int lane = (d & 15) | (g << 4);
        const int slot = lane * 8 + j;
        const int fbH = (r * 2 + s) * 4 + Mt;
        plds[fbH * 512 + slot]           = (short)hi;
        plds[(fbH + R * 8) * 512 + slot] = (short)lo;
    }
    __syncthreads();   // last barrier; divergent exits below are safe

    const int l  = tid & 63;
    const int wv = tid >> 6;
    const int li = l & 15;
    const int lg = l >> 4;

    const int t0 = blockIdx.x * TPB;
    int t1 = t0 + TPB; if (t1 > NT) t1 = NT;

    int t = t0 + wv;
    if (t >= t1) return;

    // ---- pipeline preamble ----
    int ecur = t * 16 + li;
    {
        // rows of tile t
        const int es = (ecur < E) ? ecur : (E - 1);
        // fallthrough loads below
        (void)es;
    }
    const int es0 = (ecur < E) ? ecur : (E - 1);
    const int uix0 = src[es0], vix0 = dst[es0];
    const float* vrow0 = ifeat + (size_t)vix0 * D;
    const float* urow0 = ufeat + (size_t)uix0 * D;
    float4 va0 = *reinterpret_cast<const float4*>(vrow0 + lg * 8);
    float4 va1 = *reinterpret_cast<const float4*>(vrow0 + lg * 8 + 4);
    float4 va2 = *reinterpret_cast<const float4*>(vrow0 + 32 + lg * 8);
    float4 va3 = *reinterpret_cast<const float4*>(vrow0 + 32 + lg * 8 + 4);
    float4 ua0 = *reinterpret_cast<const float4*>(urow0 + 0 * 16 + lg * 4);
    float4 ua1 = *reinterpret_cast<const float4*>(urow0 + 1 * 16 + lg * 4);
    float4 ua2 = *reinterpret_cast<const float4*>(urow0 + 2 * 16 + lg * 4);
    float4 ua3 = *reinterpret_cast<const float4*>(urow0 + 3 * 16 + lg * 4);
    // indices of tile t+WPB (depth-2 idx pipeline)
    int uixn, vixn;
    {
        const int tn = t + WPB;
        const int tp = (tn < t1) ? tn : t;
        const int en = tp * 16 + li;
        const int esn = (en < E) ? en : (E - 1);
        uixn = src[esn]; vixn = dst[esn];
    }

    while (true) {
        // ---- split current vs -> bf16 hi/lo (va* dies here) ----
        short8 vhi0, vlo0, vhi1, vlo1;
        SPLIT8(vhi0, vlo0, 0, va0.x) SPLIT8(vhi0, vlo0, 1, va0.y)
        SPLIT8(vhi0, vlo0, 2, va0.z) SPLIT8(vhi0, vlo0, 3, va0.w)
        SPLIT8(vhi0, vlo0, 4, va1.x) SPLIT8(vhi0, vlo0, 5, va1.y)
        SPLIT8(vhi0, vlo0, 6, va1.z) SPLIT8(vhi0, vlo0, 7, va1.w)
        SPLIT8(vhi1, vlo1, 0, va2.x) SPLIT8(vhi1, vlo1, 1, va2.y)
        SPLIT8(vhi1, vlo1, 2, va2.z) SPLIT8(vhi1, vlo1, 3, va2.w)
        SPLIT8(vhi1, vlo1, 4, va3.x) SPLIT8(vhi1, vlo1, 5, va3.y)
        SPLIT8(vhi1, vlo1, 6, va3.z) SPLIT8(vhi1, vlo1, 7, va3.w)

        // ---- prefetch rows of tile t+WPB (idx already resident) ----
        const float* vrowB = ifeat + (size_t)vixn * D;
        const float* urowB = ufeat + (size_t)uixn * D;
        float4 vb0 = *reinterpret_cast<const float4*>(vrowB + lg * 8);
        float4 vb1 = *reinterpret_cast<const float4*>(vrowB + lg * 8 + 4);
        float4 vb2 = *reinterpret_cast<const float4*>(vrowB + 32 + lg * 8);
        float4 vb3 = *reinterpret_cast<const float4*>(vrowB + 32 + lg * 8 + 4);
        float4 ub0 = *reinterpret_cast<const float4*>(urowB + 0 * 16 + lg * 4);
        float4 ub1 = *reinterpret_cast<const float4*>(urowB + 1 * 16 + lg * 4);
        float4 ub2 = *reinterpret_cast<const float4*>(urowB + 2 * 16 + lg * 4);
        float4 ub3 = *reinterpret_cast<const float4*>(urowB + 3 * 16 + lg * 4);
        // ---- prefetch indices of tile t+2*WPB ----
        int uixnn, vixnn;
        {
            const int tnn = t + 2 * WPB;
            const int tp = (tnn < t1) ? tnn : t;
            const int enn = tp * 16 + li;
            const int esnn = (enn < E) ? enn : (E - 1);
            uixnn = src[esnn]; vixnn = dst[esnn];
        }

        // ---- MFMA + online softmax over r (runtime loop: small hoist window) ----
        float m_run = -INFINITY, ssum = 0.f, num = 0.f;
        #pragma unroll 1
        for (int r = 0; r < R; ++r) {
            f32x4 acc0 = {0,0,0,0}, acc1 = {0,0,0,0}, acc2 = {0,0,0,0}, acc3 = {0,0,0,0};
            const int fb = 8 * r;
            MBLK(acc0, fb + 0, vhi0, vlo0)
            MBLK(acc1, fb + 1, vhi0, vlo0)
            MBLK(acc2, fb + 2, vhi0, vlo0)
            MBLK(acc3, fb + 3, vhi0, vlo0)
            __builtin_amdgcn_sched_barrier(0);
            MBLK(acc0, fb + 4, vhi1, vlo1)
            MBLK(acc1, fb + 5, vhi1, vlo1)
            MBLK(acc2, fb + 6, vhi1, vlo1)
            MBLK(acc3, fb + 7, vhi1, vlo1)

            float part = dot4(acc0, ua0);
            part += dot4(acc1, ua1);
            part += dot4(acc2, ua2);
            part += dot4(acc3, ua3);
            part += __shfl_xor(part, 16);
            part += __shfl_xor(part, 32);

            const float mn = fmaxf(m_run, part);
            const float c  = expf(m_run - mn);     // first iter: exp(-inf)=0
            const float p  = expf(part - mn);
            ssum  = fmaf(ssum, c, p);
            num   = fmaf(num, c, (float)(r + 1) * p);
            m_run = mn;
        }

        if (lg == 0 && ecur < E) out[ecur] = num / ssum;

        const int tn = t + WPB;
        if (tn >= t1) break;
        t = tn; ecur = t * 16 + li;
        va0 = vb0; va1 = vb1; va2 = vb2; va3 = vb3;
        ua0 = ub0; ua1 = ub1; ua2 = ub2; ua3 = ub3;
        uixn = uixnn; vixn = vixnn;
    }
}

extern "C" void kernel_launch(void* const* d_in, const int* in_sizes, int n_in,
                              void* d_out, int out_size, void* d_ws, size_t ws_size,
                              hipStream_t stream)
{
    const float* ufeat = (const float*)d_in[0];
    const float* ifeat = (const float*)d_in[1];
    const float* Ps    = (const float*)d_in[2];
    const int*   src   = (const int*)d_in[3];
    const int*   dst   = (const int*)d_in[4];
    float*       out   = (float*)d_out;
    const int E   = in_sizes[3];
    const int NT  = (E + 15) / 16;
    const int TPB = (NT + NBLOCKS - 1) / NBLOCKS;
    hipLaunchKernelGGL(bidecoder_mfma, dim3(NBLOCKS), dim3(BLOCK), 0, stream,
                       ufeat, ifeat, Ps, src, dst, out, E, NT, TPB);
}